// Round 4
// baseline (766.613 us; speedup 1.0000x reference)
//
#include <hip/hip_runtime.h>

#define B 4
#define L 2048
#define C 64
#define NCH 256
#define TQ 16              // timesteps per fine chunk
#define S1 (L / TQ)        // 128 fine chunks per chain
#define GF 4               // fine per coarse
#define S2 (S1 / GF)       // 32 coarse chunks

// k_sum LDS: A slab = 8 chains x 32 units (16B) swizzled, + x slab 32 units.
#define XBASE 256
__device__ __forceinline__ int idxA(int c8, int u) {
    return c8 * 32 + ((u + c8) & 31);   // reads (4k+j+c8)%8 distinct across c8
}

// Summary convention: chunk (P, q): y_out = P @ y_in + q.
// sumP row-major per chain: [chunk][n][r] -> 8 c64 as float4{re,im,re,im} x4.

// ================= Phase 1: fine chunk summaries =================
// Backward: q += P @ x_t ; P = P @ A_t.  Lane = c8*8 + r (8 chains/wave).
__global__ __launch_bounds__(64, 4) void k_sum(
    const float* __restrict__ Are, const float* __restrict__ Aim,
    const float* __restrict__ Xre, const float* __restrict__ Xim,
    float2* __restrict__ sumP, float2* __restrict__ sumQ)
{
    __shared__ __align__(16) float4 lds[XBASE + 32];
    const int lane = threadIdx.x;
    const int c8 = lane >> 3, r = lane & 7;
    const int s1 = blockIdx.x >> 5;
    const int g  = blockIdx.x & 31;
    const int n0 = g * 8;
    const int b  = n0 >> 6;
    const int cc0 = n0 & 63;
    const int n = n0 + c8;
    const int tbase = s1 * TQ;

    float Pre[8], Pim[8];
#pragma unroll
    for (int k = 0; k < 8; ++k) { Pre[k] = (k == r) ? 1.f : 0.f; Pim[k] = 0.f; }
    float qre = 0.f, qim = 0.f;

    float4 A0a, A1a, I0a, I1a, Xa = make_float4(0,0,0,0);
    float4 A0b, A1b, I0b, I1b, Xb = make_float4(0,0,0,0);

#define KS_LOAD(t, A0, A1, I0, I1, XV)                                        \
    {                                                                         \
        const long fb = ((long)(b * L + (t))) * C + cc0;                      \
        const float4* gr = (const float4*)(Are + fb * 64);                    \
        const float4* gi = (const float4*)(Aim + fb * 64);                    \
        A0 = gr[lane]; A1 = gr[lane + 64];                                    \
        I0 = gi[lane]; I1 = gi[lane + 64];                                    \
        if (lane < 16)      XV = ((const float4*)(Xre + fb * 8))[lane];       \
        else if (lane < 32) XV = ((const float4*)(Xim + fb * 8))[lane - 16];  \
    }

#define KS_STAGE(A0, A1, I0, I1, XV)                                          \
    {                                                                         \
        const int rem0 = lane & 15, ccA = lane >> 4;                          \
        const int k0 = rem0 >> 1, p0 = rem0 & 1;                              \
        lds[idxA(ccA,     k0 * 4 + p0)]     = A0;                             \
        lds[idxA(ccA + 4, k0 * 4 + p0)]     = A1;                             \
        lds[idxA(ccA,     k0 * 4 + 2 + p0)] = I0;                             \
        lds[idxA(ccA + 4, k0 * 4 + 2 + p0)] = I1;                             \
        if (lane < 32) lds[XBASE + lane] = XV;                                \
    }

#define KS_COMPUTE()                                                          \
    {                                                                         \
        const float4 x0 = lds[XBASE + c8 * 2];                                \
        const float4 x1 = lds[XBASE + c8 * 2 + 1];                            \
        const float4 x2 = lds[XBASE + 16 + c8 * 2];                           \
        const float4 x3 = lds[XBASE + 16 + c8 * 2 + 1];                       \
        const float xr[8] = {x0.x,x0.y,x0.z,x0.w,x1.x,x1.y,x1.z,x1.w};        \
        const float xi[8] = {x2.x,x2.y,x2.z,x2.w,x3.x,x3.y,x3.z,x3.w};        \
        _Pragma("unroll")                                                     \
        for (int k = 0; k < 8; ++k) {                                         \
            qre += Pre[k] * xr[k] - Pim[k] * xi[k];                           \
            qim += Pre[k] * xi[k] + Pim[k] * xr[k];                           \
        }                                                                     \
        float nr[8], ni[8];                                                   \
        _Pragma("unroll")                                                     \
        for (int j = 0; j < 8; ++j) { nr[j] = 0.f; ni[j] = 0.f; }             \
        _Pragma("unroll")                                                     \
        for (int k = 0; k < 8; ++k) {                                         \
            const float4 e0 = lds[idxA(c8, 4 * k)];                           \
            const float4 e1 = lds[idxA(c8, 4 * k + 1)];                       \
            const float4 f0 = lds[idxA(c8, 4 * k + 2)];                       \
            const float4 f1 = lds[idxA(c8, 4 * k + 3)];                       \
            const float ar[8] = {e0.x,e0.y,e0.z,e0.w,e1.x,e1.y,e1.z,e1.w};    \
            const float ai[8] = {f0.x,f0.y,f0.z,f0.w,f1.x,f1.y,f1.z,f1.w};    \
            const float pr = Pre[k], pi = Pim[k];                             \
            _Pragma("unroll")                                                 \
            for (int j = 0; j < 8; ++j) {                                     \
                nr[j] += pr * ar[j] - pi * ai[j];                             \
                ni[j] += pr * ai[j] + pi * ar[j];                             \
            }                                                                 \
        }                                                                     \
        _Pragma("unroll")                                                     \
        for (int k = 0; k < 8; ++k) { Pre[k] = nr[k]; Pim[k] = ni[k]; }       \
    }

    KS_LOAD(tbase + TQ - 1, A0a, A1a, I0a, I1a, Xa);
    KS_LOAD(tbase + TQ - 2, A0b, A1b, I0b, I1b, Xb);

#pragma unroll 1
    for (int tt = TQ - 1; tt >= 1; tt -= 2) {
        KS_STAGE(A0a, A1a, I0a, I1a, Xa);
        if (tt >= 3) KS_LOAD(tbase + tt - 2, A0a, A1a, I0a, I1a, Xa);
        KS_COMPUTE();
        KS_STAGE(A0b, A1b, I0b, I1b, Xb);
        if (tt >= 3) KS_LOAD(tbase + tt - 3, A0b, A1b, I0b, I1b, Xb);
        KS_COMPUTE();
    }

    const long rowIdx = ((long)(s1 * 256 + n)) * 8 + r;
    float4* dp = (float4*)(sumP + rowIdx * 8);
    dp[0] = make_float4(Pre[0], Pim[0], Pre[1], Pim[1]);
    dp[1] = make_float4(Pre[2], Pim[2], Pre[3], Pim[3]);
    dp[2] = make_float4(Pre[4], Pim[4], Pre[5], Pim[5]);
    dp[3] = make_float4(Pre[6], Pim[6], Pre[7], Pim[7]);
    sumQ[rowIdx] = make_float2(qre, qim);
}

// ============ Phase 2a: combine GF fine -> coarse; prefixes in place ============
__global__ __launch_bounds__(64) void k_comb(
    float2* sumP, float2* sumQ,                        // aliased read+write
    float2* __restrict__ sumP2, float2* __restrict__ sumQ2)
{
    __shared__ __align__(16) float4 M[256];
    __shared__ __align__(16) float2 ql[64];
    const int lane = threadIdx.x;
    const int c8 = lane >> 3, r = lane & 7;
    const int s2 = blockIdx.x >> 5, g = blockIdx.x & 31;
    const int n = g * 8 + c8;

#pragma unroll
    for (int s = 0; s < 4; ++s)
        M[c8 * 32 + ((r * 4 + s) ^ c8)] =
            make_float4((2*s == r) ? 1.f : 0.f, 0.f, (2*s+1 == r) ? 1.f : 0.f, 0.f);
    float q2r[8], q2i[8];
#pragma unroll
    for (int k = 0; k < 8; ++k) { q2r[k] = 0.f; q2i[k] = 0.f; }
    float mrn[8], min_[8];

#pragma unroll 1
    for (int j = 0; j < GF; ++j) {
        const long rowIdx = ((long)((s2 * GF + j) * 256 + n)) * 8 + r;
        const float4* gp = (const float4*)(sumP + rowIdx * 8);
        const float4 p0 = gp[0], p1 = gp[1], p2 = gp[2], p3 = gp[3];
        const float2 qf = sumQ[rowIdx];
        const float pfr[8] = {p0.x,p0.z,p1.x,p1.z,p2.x,p2.z,p3.x,p3.z};
        const float pfi[8] = {p0.y,p0.w,p1.y,p1.w,p2.y,p2.w,p3.y,p3.w};
        // store prefix (carry transform INTO fine chunk j) in place
        float4 om[4];
#pragma unroll
        for (int s = 0; s < 4; ++s) om[s] = M[c8 * 32 + ((r * 4 + s) ^ c8)];
        float4* gout = (float4*)(sumP + rowIdx * 8);
#pragma unroll
        for (int s = 0; s < 4; ++s) gout[s] = om[s];
        sumQ[rowIdx] = make_float2(q2r[r], q2i[r]);
        // q2 = PF_j @ q2 + qF_j
        float nr = qf.x, ni = qf.y;
#pragma unroll
        for (int k = 0; k < 8; ++k) {
            nr += pfr[k] * q2r[k] - pfi[k] * q2i[k];
            ni += pfr[k] * q2i[k] + pfi[k] * q2r[k];
        }
        ql[lane] = make_float2(nr, ni);
        const float4* qv = (const float4*)ql;
#pragma unroll
        for (int s = 0; s < 4; ++s) {
            const float4 u = qv[c8 * 4 + s];
            q2r[2*s] = u.x; q2i[2*s] = u.y; q2r[2*s+1] = u.z; q2i[2*s+1] = u.w;
        }
        // M = PF_j @ M
#pragma unroll
        for (int c = 0; c < 8; ++c) { mrn[c] = 0.f; min_[c] = 0.f; }
#pragma unroll
        for (int k = 0; k < 8; ++k) {
            const float4 m0 = M[c8 * 32 + ((k * 4 + 0) ^ c8)];
            const float4 m1 = M[c8 * 32 + ((k * 4 + 1) ^ c8)];
            const float4 m2 = M[c8 * 32 + ((k * 4 + 2) ^ c8)];
            const float4 m3 = M[c8 * 32 + ((k * 4 + 3) ^ c8)];
            const float mr_[8] = {m0.x,m0.z,m1.x,m1.z,m2.x,m2.z,m3.x,m3.z};
            const float mi_[8] = {m0.y,m0.w,m1.y,m1.w,m2.y,m2.w,m3.y,m3.w};
            const float ar = pfr[k], ai = pfi[k];
#pragma unroll
            for (int c = 0; c < 8; ++c) {
                mrn[c]  += ar * mr_[c] - ai * mi_[c];
                min_[c] += ar * mi_[c] + ai * mr_[c];
            }
        }
#pragma unroll
        for (int s = 0; s < 4; ++s)
            M[c8 * 32 + ((r * 4 + s) ^ c8)] =
                make_float4(mrn[2*s], min_[2*s], mrn[2*s+1], min_[2*s+1]);
    }
    const long rowIdx2 = ((long)(s2 * 256 + n)) * 8 + r;
    float4* g2 = (float4*)(sumP2 + rowIdx2 * 8);
#pragma unroll
    for (int s = 0; s < 4; ++s)
        g2[s] = make_float4(mrn[2*s], min_[2*s], mrn[2*s+1], min_[2*s+1]);
    sumQ2[rowIdx2] = make_float2(q2r[r], q2i[r]);
}

// ============ Phase 2b: scan coarse summaries -> carry2 ============
__global__ __launch_bounds__(64) void k_carry2(
    const float2* __restrict__ sumP2, const float2* __restrict__ sumQ2,
    float2* __restrict__ carry2)
{
    __shared__ __align__(16) float2 ql[64];
    const int lane = threadIdx.x;
    const int c8 = lane >> 3, r = lane & 7;
    const int n = blockIdx.x * 8 + c8;
    float yr[8], yi[8];
#pragma unroll
    for (int k = 0; k < 8; ++k) { yr[k] = 0.f; yi[k] = 0.f; }
#pragma unroll 1
    for (int s2 = 0; s2 < S2; ++s2) {
        const long rowIdx2 = ((long)(s2 * 256 + n)) * 8 + r;
        carry2[rowIdx2] = make_float2(yr[r], yi[r]);
        const float4* gp = (const float4*)(sumP2 + rowIdx2 * 8);
        const float4 p0 = gp[0], p1 = gp[1], p2 = gp[2], p3 = gp[3];
        const float pfr[8] = {p0.x,p0.z,p1.x,p1.z,p2.x,p2.z,p3.x,p3.z};
        const float pfi[8] = {p0.y,p0.w,p1.y,p1.w,p2.y,p2.w,p3.y,p3.w};
        const float2 q2 = sumQ2[rowIdx2];
        float nr = q2.x, ni = q2.y;
#pragma unroll
        for (int k = 0; k < 8; ++k) {
            nr += pfr[k] * yr[k] - pfi[k] * yi[k];
            ni += pfr[k] * yi[k] + pfi[k] * yr[k];
        }
        ql[lane] = make_float2(nr, ni);
        const float4* qv = (const float4*)ql;
#pragma unroll
        for (int s = 0; s < 4; ++s) {
            const float4 u = qv[c8 * 4 + s];
            yr[2*s] = u.x; yi[2*s] = u.y; yr[2*s+1] = u.z; yi[2*s+1] = u.w;
        }
    }
}

// ================= Phase 3: fixup + output =================
// Lane = c8*8 + r owns row r: A-row straight from global, y replicated via LDS.
__global__ __launch_bounds__(64, 4) void k_fix(
    const float* __restrict__ Are, const float* __restrict__ Aim,
    const float* __restrict__ Xre, const float* __restrict__ Xim,
    const float2* __restrict__ sumP, const float2* __restrict__ sumQ,
    const float2* __restrict__ carry2, float2* __restrict__ out)
{
    __shared__ __align__(16) float2 yb[64];
    const int lane = threadIdx.x;
    const int c8 = lane >> 3, r = lane & 7;
    const int blk = (int)gridDim.x - 1 - (int)blockIdx.x;   // reversed for L3 reuse
    const int s1 = blk >> 5, g = blk & 31;
    const int s2 = s1 >> 2;
    const int n0 = g * 8, b = n0 >> 6, cc0 = n0 & 63;
    const int n = n0 + c8;
    const int tbase = s1 * TQ;

    float yr[8], yi[8];
    {   // prologue: y = prefixM @ carry2 + prefixQ
        const long rowIdx = ((long)(s1 * 256 + n)) * 8 + r;
        const float4* gm = (const float4*)(sumP + rowIdx * 8);
        const float4 m0 = gm[0], m1 = gm[1], m2 = gm[2], m3 = gm[3];
        const float2 pq = sumQ[rowIdx];
        const float4* gc = (const float4*)(carry2 + ((long)(s2 * 256 + n)) * 8);
        const float4 c0 = gc[0], c1 = gc[1], c2v = gc[2], c3 = gc[3];
        const float mr_[8] = {m0.x,m0.z,m1.x,m1.z,m2.x,m2.z,m3.x,m3.z};
        const float mi_[8] = {m0.y,m0.w,m1.y,m1.w,m2.y,m2.w,m3.y,m3.w};
        const float cr[8] = {c0.x,c0.z,c1.x,c1.z,c2v.x,c2v.z,c3.x,c3.z};
        const float ci[8] = {c0.y,c0.w,c1.y,c1.w,c2v.y,c2v.w,c3.y,c3.w};
        float nr = pq.x, ni = pq.y;
#pragma unroll
        for (int k = 0; k < 8; ++k) {
            nr += mr_[k] * cr[k] - mi_[k] * ci[k];
            ni += mr_[k] * ci[k] + mi_[k] * cr[k];
        }
        yb[lane] = make_float2(nr, ni);
        const float4* qv = (const float4*)yb;
#pragma unroll
        for (int s = 0; s < 4; ++s) {
            const float4 u = qv[c8 * 4 + s];
            yr[2*s] = u.x; yi[2*s] = u.y; yr[2*s+1] = u.z; yi[2*s+1] = u.w;
        }
    }

    float4 Ra0, Ra1, Ia0, Ia1; float xra, xia;
    float4 Rb0, Rb1, Ib0, Ib1; float xrb, xib;

#define KF_LOAD(t, R0, R1, I0, I1, XR, XI)                                    \
    {                                                                         \
        const long fb = ((long)(b * L + (t))) * C + cc0;                      \
        const float4* gr = (const float4*)(Are + fb * 64) + lane * 2;         \
        R0 = gr[0]; R1 = gr[1];                                               \
        const float4* gi = (const float4*)(Aim + fb * 64) + lane * 2;         \
        I0 = gi[0]; I1 = gi[1];                                               \
        XR = Xre[fb * 8 + lane]; XI = Xim[fb * 8 + lane];                     \
    }

#define KF_STEP_WRITE(t, R0, R1, I0, I1, XR, XI)                              \
    {                                                                         \
        const float ar[8] = {R0.x,R0.y,R0.z,R0.w,R1.x,R1.y,R1.z,R1.w};        \
        const float ai[8] = {I0.x,I0.y,I0.z,I0.w,I1.x,I1.y,I1.z,I1.w};        \
        float nr = XR, ni = XI;                                               \
        _Pragma("unroll")                                                     \
        for (int k = 0; k < 8; ++k) {                                         \
            nr += ar[k] * yr[k] - ai[k] * yi[k];                              \
            ni += ar[k] * yi[k] + ai[k] * yr[k];                              \
        }                                                                     \
        const long fb = ((long)(b * L + (t))) * C + cc0;                      \
        out[fb * 8 + lane] = make_float2(nr, ni);                             \
        yb[lane] = make_float2(nr, ni);                                       \
    }

#define KF_REPL()                                                             \
    {                                                                         \
        const float4* qv = (const float4*)yb;                                 \
        _Pragma("unroll")                                                     \
        for (int s = 0; s < 4; ++s) {                                         \
            const float4 u = qv[c8 * 4 + s];                                  \
            yr[2*s] = u.x; yi[2*s] = u.y; yr[2*s+1] = u.z; yi[2*s+1] = u.w;   \
        }                                                                     \
    }

    KF_LOAD(tbase + 0, Ra0, Ra1, Ia0, Ia1, xra, xia);
    KF_LOAD(tbase + 1, Rb0, Rb1, Ib0, Ib1, xrb, xib);

#pragma unroll 1
    for (int tt = 0; tt < TQ; tt += 2) {
        KF_STEP_WRITE(tbase + tt, Ra0, Ra1, Ia0, Ia1, xra, xia);
        if (tt + 2 < TQ) KF_LOAD(tbase + tt + 2, Ra0, Ra1, Ia0, Ia1, xra, xia);
        KF_REPL();
        KF_STEP_WRITE(tbase + tt + 1, Rb0, Rb1, Ib0, Ib1, xrb, xib);
        if (tt + 3 < TQ) KF_LOAD(tbase + tt + 3, Rb0, Rb1, Ib0, Ib1, xrb, xib);
        KF_REPL();
    }
}

extern "C" void kernel_launch(void* const* d_in, const int* in_sizes, int n_in,
                              void* d_out, int out_size, void* d_ws, size_t ws_size,
                              hipStream_t stream)
{
    const float* Are = (const float*)d_in[0];
    const float* Aim = (const float*)d_in[1];
    const float* Xre = (const float*)d_in[2];
    const float* Xim = (const float*)d_in[3];
    float2* out = (float2*)d_out;

    float2* sumP   = (float2*)d_ws;                    // S1*256*64 f2 = 16.8 MB
    float2* sumQ   = sumP  + (long)S1 * 256 * 64;      // S1*256*8      2.1 MB
    float2* sumP2  = sumQ  + (long)S1 * 256 * 8;       // S2*256*64     4.2 MB
    float2* sumQ2  = sumP2 + (long)S2 * 256 * 64;      // S2*256*8      0.5 MB
    float2* carry2 = sumQ2 + (long)S2 * 256 * 8;       // S2*256*8      0.5 MB

    k_sum<<<S1 * 32, 64, 0, stream>>>(Are, Aim, Xre, Xim, sumP, sumQ);
    k_comb<<<S2 * 32, 64, 0, stream>>>(sumP, sumQ, sumP2, sumQ2);
    k_carry2<<<NCH / 8, 64, 0, stream>>>(sumP2, sumQ2, carry2);
    k_fix<<<S1 * 32, 64, 0, stream>>>(Are, Aim, Xre, Xim, sumP, sumQ, carry2, out);
}

// Round 5
// 424.311 us; speedup vs baseline: 1.8067x; 1.8067x over previous
//
#include <hip/hip_runtime.h>

#define B 4
#define L 2048
#define C 64
#define NCH 256
#define TQ 16              // timesteps per fine chunk
#define S1 (L / TQ)        // 128 fine chunks per chain
#define GF 4               // fine per coarse
#define S2 (S1 / GF)       // 32 coarse chunks

// k_sum LDS float layout (chain stride 68 = 17 float4 units, 17 odd =>
// the 8 broadcast row-reads land in 8 DISTINCT bank-quads):
//   A re: chain c base unit c*17          (floats c*68 .. +63, 4 pad)
//   A im: chain c base unit 136 + c*17
//   X re: floats 1088..1151 ; X im: 1152..1215
#define U_IM 136
#define U_XR 272
#define U_XI 288

// Summary convention: chunk (P, q): y_out = P @ y_in + q.
// sumP per chain-row: [chunk][n][r] -> 8 c64 as float4{re,im,re,im} x4.

// ================= Phase 1: fine chunk summaries =================
// Backward: q += P @ x_t ; P = P @ A_t.  Lane = c8*8 + r (8 chains/wave).
__global__ __launch_bounds__(64) void k_sum(
    const float* __restrict__ Are, const float* __restrict__ Aim,
    const float* __restrict__ Xre, const float* __restrict__ Xim,
    float2* __restrict__ sumP, float2* __restrict__ sumQ)
{
    __shared__ __align__(16) float sm[1216];
    float4* s4 = (float4*)sm;
    const int lane = threadIdx.x;
    const int c8 = lane >> 3, r = lane & 7;
    const int s1 = blockIdx.x >> 5;
    const int g  = blockIdx.x & 31;
    const int n0 = g * 8;
    const int b  = n0 >> 6;
    const int cc0 = n0 & 63;
    const int n = n0 + c8;
    const int tbase = s1 * TQ;
    const int ca = lane >> 4;          // staging chain sub-index 0..3
    const int uu = lane & 15;          // staging unit-in-chain 0..15

    float Pre[8], Pim[8];
#pragma unroll
    for (int k = 0; k < 8; ++k) { Pre[k] = (k == r) ? 1.f : 0.f; Pim[k] = 0.f; }
    float qre = 0.f, qim = 0.f;

    float4 A0, A1, I0, I1; float XR, XI;

#define KS_LOAD(t)                                                            \
    {                                                                         \
        const long fb = ((long)(b * L + (t))) * C + cc0;                      \
        const float4* gr = (const float4*)(Are + fb * 64);                    \
        const float4* gi = (const float4*)(Aim + fb * 64);                    \
        A0 = gr[lane]; A1 = gr[lane + 64];                                    \
        I0 = gi[lane]; I1 = gi[lane + 64];                                    \
        XR = Xre[fb * 8 + lane]; XI = Xim[fb * 8 + lane];                     \
    }

#define KS_STAGE()                                                            \
    {                                                                         \
        s4[ca * 17 + uu]              = A0;                                   \
        s4[(ca + 4) * 17 + uu]        = A1;                                   \
        s4[U_IM + ca * 17 + uu]       = I0;                                   \
        s4[U_IM + (ca + 4) * 17 + uu] = I1;                                   \
        sm[1088 + lane] = XR; sm[1152 + lane] = XI;                           \
    }

#define KS_COMPUTE()                                                          \
    {                                                                         \
        const float4 x0 = s4[U_XR + c8 * 2], x1 = s4[U_XR + c8 * 2 + 1];      \
        const float4 x2 = s4[U_XI + c8 * 2], x3 = s4[U_XI + c8 * 2 + 1];      \
        const float xr[8] = {x0.x,x0.y,x0.z,x0.w,x1.x,x1.y,x1.z,x1.w};        \
        const float xi[8] = {x2.x,x2.y,x2.z,x2.w,x3.x,x3.y,x3.z,x3.w};        \
        _Pragma("unroll")                                                     \
        for (int k = 0; k < 8; ++k) {                                         \
            qre += Pre[k] * xr[k] - Pim[k] * xi[k];                           \
            qim += Pre[k] * xi[k] + Pim[k] * xr[k];                           \
        }                                                                     \
        float nr[8], ni[8];                                                   \
        _Pragma("unroll")                                                     \
        for (int j = 0; j < 8; ++j) { nr[j] = 0.f; ni[j] = 0.f; }             \
        _Pragma("unroll")                                                     \
        for (int k = 0; k < 8; ++k) {                                         \
            const float4 e0 = s4[c8 * 17 + 2 * k];                            \
            const float4 e1 = s4[c8 * 17 + 2 * k + 1];                        \
            const float4 f0 = s4[U_IM + c8 * 17 + 2 * k];                     \
            const float4 f1 = s4[U_IM + c8 * 17 + 2 * k + 1];                 \
            const float ar[8] = {e0.x,e0.y,e0.z,e0.w,e1.x,e1.y,e1.z,e1.w};    \
            const float ai[8] = {f0.x,f0.y,f0.z,f0.w,f1.x,f1.y,f1.z,f1.w};    \
            const float pr = Pre[k], pi = Pim[k];                             \
            _Pragma("unroll")                                                 \
            for (int j = 0; j < 8; ++j) {                                     \
                nr[j] += pr * ar[j] - pi * ai[j];                             \
                ni[j] += pr * ai[j] + pi * ar[j];                             \
            }                                                                 \
        }                                                                     \
        _Pragma("unroll")                                                     \
        for (int k = 0; k < 8; ++k) { Pre[k] = nr[k]; Pim[k] = ni[k]; }       \
    }

    KS_LOAD(tbase + TQ - 1);
#pragma unroll 1
    for (int tt = TQ - 1; tt >= 0; --tt) {
        KS_STAGE();
        if (tt > 0) KS_LOAD(tbase + tt - 1);
        KS_COMPUTE();
    }

    const long rowIdx = ((long)(s1 * 256 + n)) * 8 + r;
    float4* dp = (float4*)(sumP + rowIdx * 8);
    dp[0] = make_float4(Pre[0], Pim[0], Pre[1], Pim[1]);
    dp[1] = make_float4(Pre[2], Pim[2], Pre[3], Pim[3]);
    dp[2] = make_float4(Pre[4], Pim[4], Pre[5], Pim[5]);
    dp[3] = make_float4(Pre[6], Pim[6], Pre[7], Pim[7]);
    sumQ[rowIdx] = make_float2(qre, qim);
}

// ============ Phase 2a: combine GF fine -> coarse; prefixes in place ============
__global__ __launch_bounds__(64) void k_comb(
    float2* sumP, float2* sumQ,                        // aliased read+write
    float2* __restrict__ sumP2, float2* __restrict__ sumQ2)
{
    __shared__ __align__(16) float4 M[256];
    __shared__ __align__(16) float2 ql[64];
    const int lane = threadIdx.x;
    const int c8 = lane >> 3, r = lane & 7;
    const int s2 = blockIdx.x >> 5, g = blockIdx.x & 31;
    const int n = g * 8 + c8;

#pragma unroll
    for (int s = 0; s < 4; ++s)
        M[c8 * 32 + ((r * 4 + s) ^ c8)] =
            make_float4((2*s == r) ? 1.f : 0.f, 0.f, (2*s+1 == r) ? 1.f : 0.f, 0.f);
    float q2r[8], q2i[8];
#pragma unroll
    for (int k = 0; k < 8; ++k) { q2r[k] = 0.f; q2i[k] = 0.f; }
    float mrn[8], min_[8];

#pragma unroll 1
    for (int j = 0; j < GF; ++j) {
        const long rowIdx = ((long)((s2 * GF + j) * 256 + n)) * 8 + r;
        const float4* gp = (const float4*)(sumP + rowIdx * 8);
        const float4 p0 = gp[0], p1 = gp[1], p2 = gp[2], p3 = gp[3];
        const float2 qf = sumQ[rowIdx];
        const float pfr[8] = {p0.x,p0.z,p1.x,p1.z,p2.x,p2.z,p3.x,p3.z};
        const float pfi[8] = {p0.y,p0.w,p1.y,p1.w,p2.y,p2.w,p3.y,p3.w};
        // store prefix (carry transform INTO fine chunk j) in place
        float4 om[4];
#pragma unroll
        for (int s = 0; s < 4; ++s) om[s] = M[c8 * 32 + ((r * 4 + s) ^ c8)];
        float4* gout = (float4*)(sumP + rowIdx * 8);
#pragma unroll
        for (int s = 0; s < 4; ++s) gout[s] = om[s];
        sumQ[rowIdx] = make_float2(q2r[r], q2i[r]);
        // q2 = PF_j @ q2 + qF_j
        float nr = qf.x, ni = qf.y;
#pragma unroll
        for (int k = 0; k < 8; ++k) {
            nr += pfr[k] * q2r[k] - pfi[k] * q2i[k];
            ni += pfr[k] * q2i[k] + pfi[k] * q2r[k];
        }
        ql[lane] = make_float2(nr, ni);
        const float4* qv = (const float4*)ql;
#pragma unroll
        for (int s = 0; s < 4; ++s) {
            const float4 u = qv[c8 * 4 + s];
            q2r[2*s] = u.x; q2i[2*s] = u.y; q2r[2*s+1] = u.z; q2i[2*s+1] = u.w;
        }
        // M = PF_j @ M
#pragma unroll
        for (int c = 0; c < 8; ++c) { mrn[c] = 0.f; min_[c] = 0.f; }
#pragma unroll
        for (int k = 0; k < 8; ++k) {
            const float4 m0 = M[c8 * 32 + ((k * 4 + 0) ^ c8)];
            const float4 m1 = M[c8 * 32 + ((k * 4 + 1) ^ c8)];
            const float4 m2 = M[c8 * 32 + ((k * 4 + 2) ^ c8)];
            const float4 m3 = M[c8 * 32 + ((k * 4 + 3) ^ c8)];
            const float mr_[8] = {m0.x,m0.z,m1.x,m1.z,m2.x,m2.z,m3.x,m3.z};
            const float mi_[8] = {m0.y,m0.w,m1.y,m1.w,m2.y,m2.w,m3.y,m3.w};
            const float ar = pfr[k], ai = pfi[k];
#pragma unroll
            for (int c = 0; c < 8; ++c) {
                mrn[c]  += ar * mr_[c] - ai * mi_[c];
                min_[c] += ar * mi_[c] + ai * mr_[c];
            }
        }
#pragma unroll
        for (int s = 0; s < 4; ++s)
            M[c8 * 32 + ((r * 4 + s) ^ c8)] =
                make_float4(mrn[2*s], min_[2*s], mrn[2*s+1], min_[2*s+1]);
    }
    const long rowIdx2 = ((long)(s2 * 256 + n)) * 8 + r;
    float4* g2 = (float4*)(sumP2 + rowIdx2 * 8);
#pragma unroll
    for (int s = 0; s < 4; ++s)
        g2[s] = make_float4(mrn[2*s], min_[2*s], mrn[2*s+1], min_[2*s+1]);
    sumQ2[rowIdx2] = make_float2(q2r[r], q2i[r]);
}

// ============ Phase 2b: scan coarse summaries -> carry2 ============
__global__ __launch_bounds__(64) void k_carry2(
    const float2* __restrict__ sumP2, const float2* __restrict__ sumQ2,
    float2* __restrict__ carry2)
{
    __shared__ __align__(16) float2 ql[64];
    const int lane = threadIdx.x;
    const int c8 = lane >> 3, r = lane & 7;
    const int n = blockIdx.x * 8 + c8;
    float yr[8], yi[8];
#pragma unroll
    for (int k = 0; k < 8; ++k) { yr[k] = 0.f; yi[k] = 0.f; }
#pragma unroll 1
    for (int s2 = 0; s2 < S2; ++s2) {
        const long rowIdx2 = ((long)(s2 * 256 + n)) * 8 + r;
        carry2[rowIdx2] = make_float2(yr[r], yi[r]);
        const float4* gp = (const float4*)(sumP2 + rowIdx2 * 8);
        const float4 p0 = gp[0], p1 = gp[1], p2 = gp[2], p3 = gp[3];
        const float pfr[8] = {p0.x,p0.z,p1.x,p1.z,p2.x,p2.z,p3.x,p3.z};
        const float pfi[8] = {p0.y,p0.w,p1.y,p1.w,p2.y,p2.w,p3.y,p3.w};
        const float2 q2 = sumQ2[rowIdx2];
        float nr = q2.x, ni = q2.y;
#pragma unroll
        for (int k = 0; k < 8; ++k) {
            nr += pfr[k] * yr[k] - pfi[k] * yi[k];
            ni += pfr[k] * yi[k] + pfi[k] * yr[k];
        }
        ql[lane] = make_float2(nr, ni);
        const float4* qv = (const float4*)ql;
#pragma unroll
        for (int s = 0; s < 4; ++s) {
            const float4 u = qv[c8 * 4 + s];
            yr[2*s] = u.x; yi[2*s] = u.y; yr[2*s+1] = u.z; yi[2*s+1] = u.w;
        }
    }
}

// ================= Phase 3: fixup + output =================
// Lane = c8*8 + r owns row r: A-row straight from global, y replicated via LDS.
__global__ __launch_bounds__(64) void k_fix(
    const float* __restrict__ Are, const float* __restrict__ Aim,
    const float* __restrict__ Xre, const float* __restrict__ Xim,
    const float2* __restrict__ sumP, const float2* __restrict__ sumQ,
    const float2* __restrict__ carry2, float2* __restrict__ out)
{
    __shared__ __align__(16) float2 yb[64];
    const int lane = threadIdx.x;
    const int c8 = lane >> 3, r = lane & 7;
    const int blk = (int)gridDim.x - 1 - (int)blockIdx.x;   // reversed for L3 reuse
    const int s1 = blk >> 5, g = blk & 31;
    const int s2 = s1 >> 2;
    const int n0 = g * 8, b = n0 >> 6, cc0 = n0 & 63;
    const int n = n0 + c8;
    const int tbase = s1 * TQ;

    float yr[8], yi[8];
    {   // prologue: y = prefixM @ carry2 + prefixQ
        const long rowIdx = ((long)(s1 * 256 + n)) * 8 + r;
        const float4* gm = (const float4*)(sumP + rowIdx * 8);
        const float4 m0 = gm[0], m1 = gm[1], m2 = gm[2], m3 = gm[3];
        const float2 pq = sumQ[rowIdx];
        const float4* gc = (const float4*)(carry2 + ((long)(s2 * 256 + n)) * 8);
        const float4 c0 = gc[0], c1 = gc[1], c2v = gc[2], c3 = gc[3];
        const float mr_[8] = {m0.x,m0.z,m1.x,m1.z,m2.x,m2.z,m3.x,m3.z};
        const float mi_[8] = {m0.y,m0.w,m1.y,m1.w,m2.y,m2.w,m3.y,m3.w};
        const float cr[8] = {c0.x,c0.z,c1.x,c1.z,c2v.x,c2v.z,c3.x,c3.z};
        const float ci[8] = {c0.y,c0.w,c1.y,c1.w,c2v.y,c2v.w,c3.y,c3.w};
        float nr = pq.x, ni = pq.y;
#pragma unroll
        for (int k = 0; k < 8; ++k) {
            nr += mr_[k] * cr[k] - mi_[k] * ci[k];
            ni += mr_[k] * ci[k] + mi_[k] * cr[k];
        }
        yb[lane] = make_float2(nr, ni);
        const float4* qv = (const float4*)yb;
#pragma unroll
        for (int s = 0; s < 4; ++s) {
            const float4 u = qv[c8 * 4 + s];
            yr[2*s] = u.x; yi[2*s] = u.y; yr[2*s+1] = u.z; yi[2*s+1] = u.w;
        }
    }

    float4 R0, R1, I0, I1; float xr_, xi_;

#define KF_LOAD(t)                                                            \
    {                                                                         \
        const long fb = ((long)(b * L + (t))) * C + cc0;                      \
        const float4* gr = (const float4*)(Are + fb * 64) + lane * 2;         \
        R0 = gr[0]; R1 = gr[1];                                               \
        const float4* gi = (const float4*)(Aim + fb * 64) + lane * 2;         \
        I0 = gi[0]; I1 = gi[1];                                               \
        xr_ = Xre[fb * 8 + lane]; xi_ = Xim[fb * 8 + lane];                   \
    }

    KF_LOAD(tbase + 0);
#pragma unroll 1
    for (int tt = 0; tt < TQ; ++tt) {
        const float ar[8] = {R0.x,R0.y,R0.z,R0.w,R1.x,R1.y,R1.z,R1.w};
        const float ai[8] = {I0.x,I0.y,I0.z,I0.w,I1.x,I1.y,I1.z,I1.w};
        float nr = xr_, ni = xi_;
#pragma unroll
        for (int k = 0; k < 8; ++k) {
            nr += ar[k] * yr[k] - ai[k] * yi[k];
            ni += ar[k] * yi[k] + ai[k] * yr[k];
        }
        const long fb = ((long)(b * L + tbase + tt)) * C + cc0;
        if (tt + 1 < TQ) KF_LOAD(tbase + tt + 1);     // prefetch next step
        out[fb * 8 + lane] = make_float2(nr, ni);
        yb[lane] = make_float2(nr, ni);
        const float4* qv = (const float4*)yb;
#pragma unroll
        for (int s = 0; s < 4; ++s) {
            const float4 u = qv[c8 * 4 + s];
            yr[2*s] = u.x; yi[2*s] = u.y; yr[2*s+1] = u.z; yi[2*s+1] = u.w;
        }
    }
}

extern "C" void kernel_launch(void* const* d_in, const int* in_sizes, int n_in,
                              void* d_out, int out_size, void* d_ws, size_t ws_size,
                              hipStream_t stream)
{
    const float* Are = (const float*)d_in[0];
    const float* Aim = (const float*)d_in[1];
    const float* Xre = (const float*)d_in[2];
    const float* Xim = (const float*)d_in[3];
    float2* out = (float2*)d_out;

    float2* sumP   = (float2*)d_ws;                    // S1*256*64 f2 = 16.8 MB
    float2* sumQ   = sumP  + (long)S1 * 256 * 64;      // S1*256*8      2.1 MB
    float2* sumP2  = sumQ  + (long)S1 * 256 * 8;       // S2*256*64     4.2 MB
    float2* sumQ2  = sumP2 + (long)S2 * 256 * 64;      // S2*256*8      0.5 MB
    float2* carry2 = sumQ2 + (long)S2 * 256 * 8;       // S2*256*8      0.5 MB

    k_sum<<<S1 * 32, 64, 0, stream>>>(Are, Aim, Xre, Xim, sumP, sumQ);
    k_comb<<<S2 * 32, 64, 0, stream>>>(sumP, sumQ, sumP2, sumQ2);
    k_carry2<<<NCH / 8, 64, 0, stream>>>(sumP2, sumQ2, carry2);
    k_fix<<<S1 * 32, 64, 0, stream>>>(Are, Aim, Xre, Xim, sumP, sumQ, carry2, out);
}